// Round 1
// baseline (2340.578 us; speedup 1.0000x reference)
//
#include <hip/hip_runtime.h>
#include <math.h>

#define NNODES 50000
#define NEDGES 800000
#define HDIM 128
#define NINV 32

#define ET 32            // edges per block
#define SSTRIDE 292      // 288 + 4 pad (float4-aligned, de-phases banks)
#define HSTRIDE 132      // 128 + 4 pad
#define NT 32            // nodes per block
#define USTRIDE 260      // 256 + 4 pad

__device__ __forceinline__ float silu_f(float z) { return z / (1.0f + __expf(-z)); }

#define FMA4(acc, s, w) do { \
    acc.x = fmaf(s, w.x, acc.x); acc.y = fmaf(s, w.y, acc.y); \
    acc.z = fmaf(s, w.z, acc.z); acc.w = fmaf(s, w.w, acc.w); } while (0)

// adj may arrive as int32 or int64 depending on harness x64 config; a device-side
// probe writes a flag and all index reads go through this helper.
__device__ __forceinline__ int adj_at(const void* adj, int is64, long long pos) {
    if (is64) return (int)((const long long*)adj)[pos];
    return ((const int*)adj)[pos];
}

__global__ __launch_bounds__(256) void detect_idx64(const int* __restrict__ adj32,
                                                    int* __restrict__ flag) {
    __shared__ int any_nz;
    if (threadIdx.x == 0) any_nz = 0;
    __syncthreads();
    // If adj is int64 (values < 2^31), every odd int32 slot (high word) is 0.
    // If adj is int32, these slots are random node indices: P(all zero) ~ 0.
    int v = adj32[threadIdx.x * 2 + 1];
    if (v != 0) atomicOr(&any_nz, 1);
    __syncthreads();
    if (threadIdx.x == 0) *flag = (any_nz == 0) ? 1 : 0;
}

__global__ __launch_bounds__(256) void edge_kernel(
    const float* __restrict__ x, const void* __restrict__ adj,
    const int* __restrict__ flagp, const float* __restrict__ inv,
    const float* __restrict__ Wm1, const float* __restrict__ bm1,
    const float* __restrict__ Wm2, const float* __restrict__ bm2,
    const float* __restrict__ We, const float* __restrict__ be,
    float* __restrict__ aggr)
{
    __shared__ float s_state[ET][SSTRIDE];  // [x_send | x_rec | inv]; later reused for msg
    __shared__ float s_h[ET][HSTRIDE];
    __shared__ float s_gate[ET];
    __shared__ int   s_rec[ET];

    const int t  = threadIdx.x;
    const int e0 = blockIdx.x * ET;
    const int is64 = *flagp;

    if (t < ET) s_rec[t] = adj_at(adj, is64, (long long)NEDGES + e0 + t);

    // Stage state: 32 edges x 72 float4 (= 288 floats) each.
    for (int idx = t; idx < ET * 72; idx += 256) {
        int e = idx / 72, c = idx % 72;
        float4 v;
        if (c < 32) {
            int s = adj_at(adj, is64, e0 + e);
            v = ((const float4*)(x + (long long)s * HDIM))[c];
        } else if (c < 64) {
            int r = adj_at(adj, is64, (long long)NEDGES + e0 + e);
            v = ((const float4*)(x + (long long)r * HDIM))[c - 32];
        } else {
            v = ((const float4*)(inv + (long long)(e0 + e) * NINV))[c - 64];
        }
        *(float4*)&s_state[e][c * 4] = v;
    }
    __syncthreads();

    const int jg = t & 31;   // feature cols 4*jg..4*jg+3
    const int eg = t >> 5;   // edge rows 4*eg..4*eg+3
    const int eb = eg * 4;

    float4 a0, a1, a2, a3;

    // ---- Layer 1: state[32x288] @ Wm1[288x128] + bm1, SiLU -> s_h ----
    {
        float4 b = ((const float4*)bm1)[jg];
        a0 = b; a1 = b; a2 = b; a3 = b;
        const float4* W = (const float4*)Wm1;
        #pragma unroll 4
        for (int k = 0; k < 2 * HDIM + NINV; ++k) {
            float4 w = W[k * 32 + jg];
            float s0 = s_state[eb + 0][k];
            float s1 = s_state[eb + 1][k];
            float s2 = s_state[eb + 2][k];
            float s3 = s_state[eb + 3][k];
            FMA4(a0, s0, w); FMA4(a1, s1, w); FMA4(a2, s2, w); FMA4(a3, s3, w);
        }
        *(float4*)&s_h[eb + 0][jg * 4] = make_float4(silu_f(a0.x), silu_f(a0.y), silu_f(a0.z), silu_f(a0.w));
        *(float4*)&s_h[eb + 1][jg * 4] = make_float4(silu_f(a1.x), silu_f(a1.y), silu_f(a1.z), silu_f(a1.w));
        *(float4*)&s_h[eb + 2][jg * 4] = make_float4(silu_f(a2.x), silu_f(a2.y), silu_f(a2.z), silu_f(a2.w));
        *(float4*)&s_h[eb + 3][jg * 4] = make_float4(silu_f(a3.x), silu_f(a3.y), silu_f(a3.z), silu_f(a3.w));
    }
    __syncthreads();

    // ---- Layer 2: h[32x128] @ Wm2[128x128] + bm2, SiLU -> msg (reuse s_state cols 0..127) ----
    {
        float4 b = ((const float4*)bm2)[jg];
        a0 = b; a1 = b; a2 = b; a3 = b;
        const float4* W = (const float4*)Wm2;
        #pragma unroll 4
        for (int k = 0; k < HDIM; ++k) {
            float4 w = W[k * 32 + jg];
            float s0 = s_h[eb + 0][k];
            float s1 = s_h[eb + 1][k];
            float s2 = s_h[eb + 2][k];
            float s3 = s_h[eb + 3][k];
            FMA4(a0, s0, w); FMA4(a1, s1, w); FMA4(a2, s2, w); FMA4(a3, s3, w);
        }
        *(float4*)&s_state[eb + 0][jg * 4] = make_float4(silu_f(a0.x), silu_f(a0.y), silu_f(a0.z), silu_f(a0.w));
        *(float4*)&s_state[eb + 1][jg * 4] = make_float4(silu_f(a1.x), silu_f(a1.y), silu_f(a1.z), silu_f(a1.w));
        *(float4*)&s_state[eb + 2][jg * 4] = make_float4(silu_f(a2.x), silu_f(a2.y), silu_f(a2.z), silu_f(a2.w));
        *(float4*)&s_state[eb + 3][jg * 4] = make_float4(silu_f(a3.x), silu_f(a3.y), silu_f(a3.z), silu_f(a3.w));
    }
    __syncthreads();

    // ---- Gate: sigmoid(msg @ We + be), 8 threads per edge ----
    {
        int e = t >> 3, part = t & 7;
        float sum = 0.f;
        #pragma unroll
        for (int kk = 0; kk < 16; ++kk) {
            int k = part * 16 + kk;
            sum += s_state[e][k] * We[k];
        }
        sum += __shfl_down(sum, 4, 8);
        sum += __shfl_down(sum, 2, 8);
        sum += __shfl_down(sum, 1, 8);
        if (part == 0) s_gate[e] = 1.0f / (1.0f + __expf(-(sum + be[0])));
    }
    __syncthreads();

    // ---- Scatter: atomicAdd(msg * gate) into aggr[rec] ----
    #pragma unroll
    for (int i = 0; i < 16; ++i) {
        int lin = t + 256 * i;
        int e = lin >> 7;
        int j = lin & 127;
        float v = s_state[e][j] * s_gate[e];
        atomicAdd(aggr + (long long)s_rec[e] * HDIM + j, v);
    }
}

__global__ __launch_bounds__(256) void node_kernel(
    const float* __restrict__ x, const float* __restrict__ aggr,
    const float* __restrict__ Wu1, const float* __restrict__ bu1,
    const float* __restrict__ Wu2, const float* __restrict__ bu2,
    float* __restrict__ out)
{
    __shared__ float s_in[NT][USTRIDE];   // [x | aggr]
    __shared__ float s_t[NT][HSTRIDE];

    const int t  = threadIdx.x;
    const int n0 = blockIdx.x * NT;

    for (int idx = t; idx < NT * 64; idx += 256) {
        int n = idx / 64, c = idx % 64;
        if (n0 + n < NNODES) {
            float4 v = (c < 32) ? ((const float4*)(x    + (long long)(n0 + n) * HDIM))[c]
                                : ((const float4*)(aggr + (long long)(n0 + n) * HDIM))[c - 32];
            *(float4*)&s_in[n][c * 4] = v;
        }
    }
    __syncthreads();

    const int jg = t & 31;
    const int ng = t >> 5;
    const int nb = ng * 4;

    float4 a0, a1, a2, a3;

    // ---- Layer 1: upd_in[32x256] @ Wu1[256x128] + bu1, SiLU -> s_t ----
    {
        float4 b = ((const float4*)bu1)[jg];
        a0 = b; a1 = b; a2 = b; a3 = b;
        const float4* W = (const float4*)Wu1;
        #pragma unroll 4
        for (int k = 0; k < 2 * HDIM; ++k) {
            float4 w = W[k * 32 + jg];
            float s0 = s_in[nb + 0][k];
            float s1 = s_in[nb + 1][k];
            float s2 = s_in[nb + 2][k];
            float s3 = s_in[nb + 3][k];
            FMA4(a0, s0, w); FMA4(a1, s1, w); FMA4(a2, s2, w); FMA4(a3, s3, w);
        }
        *(float4*)&s_t[nb + 0][jg * 4] = make_float4(silu_f(a0.x), silu_f(a0.y), silu_f(a0.z), silu_f(a0.w));
        *(float4*)&s_t[nb + 1][jg * 4] = make_float4(silu_f(a1.x), silu_f(a1.y), silu_f(a1.z), silu_f(a1.w));
        *(float4*)&s_t[nb + 2][jg * 4] = make_float4(silu_f(a2.x), silu_f(a2.y), silu_f(a2.z), silu_f(a2.w));
        *(float4*)&s_t[nb + 3][jg * 4] = make_float4(silu_f(a3.x), silu_f(a3.y), silu_f(a3.z), silu_f(a3.w));
    }
    __syncthreads();

    // ---- Layer 2: t[32x128] @ Wu2[128x128] + bu2; out = x + result ----
    {
        float4 b = ((const float4*)bu2)[jg];
        a0 = b; a1 = b; a2 = b; a3 = b;
        const float4* W = (const float4*)Wu2;
        #pragma unroll 4
        for (int k = 0; k < HDIM; ++k) {
            float4 w = W[k * 32 + jg];
            float s0 = s_t[nb + 0][k];
            float s1 = s_t[nb + 1][k];
            float s2 = s_t[nb + 2][k];
            float s3 = s_t[nb + 3][k];
            FMA4(a0, s0, w); FMA4(a1, s1, w); FMA4(a2, s2, w); FMA4(a3, s3, w);
        }
        #pragma unroll
        for (int i = 0; i < 4; ++i) {
            int n = nb + i;
            if (n0 + n < NNODES) {
                float4 acc = (i == 0) ? a0 : (i == 1) ? a1 : (i == 2) ? a2 : a3;
                float4 xv = *(float4*)&s_in[n][jg * 4];
                float4 o = make_float4(xv.x + acc.x, xv.y + acc.y, xv.z + acc.z, xv.w + acc.w);
                ((float4*)(out + (long long)(n0 + n) * HDIM))[jg] = o;
            }
        }
    }
}

extern "C" void kernel_launch(void* const* d_in, const int* in_sizes, int n_in,
                              void* d_out, int out_size, void* d_ws, size_t ws_size,
                              hipStream_t stream)
{
    const float* x   = (const float*)d_in[0];
    const void*  adj = d_in[1];
    const float* inv = (const float*)d_in[2];
    const float* Wm1 = (const float*)d_in[3];
    const float* bm1 = (const float*)d_in[4];
    const float* Wm2 = (const float*)d_in[5];
    const float* bm2 = (const float*)d_in[6];
    const float* We  = (const float*)d_in[7];
    const float* be  = (const float*)d_in[8];
    const float* Wu1 = (const float*)d_in[9];
    const float* bu1 = (const float*)d_in[10];
    const float* Wu2 = (const float*)d_in[11];
    const float* bu2 = (const float*)d_in[12];
    float* out = (float*)d_out;

    float* aggr = (float*)d_ws;
    int* flag = (int*)((char*)d_ws + (size_t)NNODES * HDIM * sizeof(float));

    hipMemsetAsync(aggr, 0, (size_t)NNODES * HDIM * sizeof(float), stream);
    detect_idx64<<<1, 256, 0, stream>>>((const int*)adj, flag);
    edge_kernel<<<NEDGES / ET, 256, 0, stream>>>(x, adj, flag, inv,
                                                 Wm1, bm1, Wm2, bm2, We, be, aggr);
    node_kernel<<<(NNODES + NT - 1) / NT, 256, 0, stream>>>(x, aggr,
                                                            Wu1, bu1, Wu2, bu2, out);
}

// Round 2
// 1010.951 us; speedup vs baseline: 2.3152x; 2.3152x over previous
//
#include <hip/hip_runtime.h>
#include <math.h>

#define NNODES 50000
#define NEDGES 800000
#define HDIM 128
#define NINV 32
#define K1 (2*HDIM + NINV)   // 288

#define ET 64          // edges per block (edge kernel)
#define SROW 296       // state row stride in ushorts (288 + 8 pad; 592B row, 16B aligned)
#define BROW 40        // weight-tile row stride in ushorts (32 + 8 pad; breaks bank phase)

#define NT 32          // nodes per block (node kernel)
#define USTRIDE 260
#define HSTRIDE 132

typedef float  floatx4 __attribute__((ext_vector_type(4)));
typedef short  short8  __attribute__((ext_vector_type(8)));

__device__ __forceinline__ float silu_f(float z) { return z / (1.0f + __expf(-z)); }

__device__ __forceinline__ unsigned short f2bf(float f) {
    unsigned u = __float_as_uint(f);
    u += 0x7fffu + ((u >> 16) & 1u);        // round-to-nearest-even
    return (unsigned short)(u >> 16);
}

#define FMA4(acc, s, w) do { \
    acc.x = fmaf(s, w.x, acc.x); acc.y = fmaf(s, w.y, acc.y); \
    acc.z = fmaf(s, w.z, acc.z); acc.w = fmaf(s, w.w, acc.w); } while (0)

__device__ __forceinline__ int adj_at(const void* adj, int is64, long long pos) {
    if (is64) return (int)((const long long*)adj)[pos];
    return ((const int*)adj)[pos];
}

__global__ __launch_bounds__(256) void detect_idx64(const int* __restrict__ adj32,
                                                    int* __restrict__ flag) {
    __shared__ int any_nz;
    if (threadIdx.x == 0) any_nz = 0;
    __syncthreads();
    int v = adj32[threadIdx.x * 2 + 1];
    if (v != 0) atomicOr(&any_nz, 1);
    __syncthreads();
    if (threadIdx.x == 0) *flag = (any_nz == 0) ? 1 : 0;
}

// Transpose + bf16-convert the edge-MLP weights: Wt[n][k] = bf16(W[k][n]).
__global__ __launch_bounds__(256) void prep_weights(
    const float* __restrict__ Wm1, const float* __restrict__ Wm2,
    unsigned short* __restrict__ Wm1t, unsigned short* __restrict__ Wm2t)
{
    int i = blockIdx.x * 256 + threadIdx.x;
    if (i < 128 * K1) {
        int n = i / K1, k = i % K1;
        Wm1t[i] = f2bf(Wm1[k * HDIM + n]);
    } else {
        int j = i - 128 * K1;
        if (j < 128 * HDIM) {
            int n = j / HDIM, k = j % HDIM;
            Wm2t[j] = f2bf(Wm2[k * HDIM + n]);
        }
    }
}

__global__ __launch_bounds__(256) void edge_kernel(
    const float* __restrict__ x, const void* __restrict__ adj,
    const int* __restrict__ flagp, const float* __restrict__ inv,
    const unsigned short* __restrict__ Wm1t, const float* __restrict__ bm1,
    const unsigned short* __restrict__ Wm2t, const float* __restrict__ bm2,
    const float* __restrict__ We, const float* __restrict__ be,
    float* __restrict__ aggr)
{
    __shared__ unsigned short s_state[ET][SROW];  // [x_send|x_rec|inv] bf16; cols 0..127 reused for h
    __shared__ unsigned short s_b[128][BROW];     // current Wt K-tile: [n][k-chunk of 32]
    __shared__ int s_rec[ET];

    const int t    = threadIdx.x;
    const int e0   = blockIdx.x * ET;
    const int is64 = *flagp;
    const int l    = t & 63;
    const int w    = t >> 6;        // wave 0..3 owns edge rows w*16..w*16+15
    const int l15  = l & 15;
    const int quad = l >> 4;
    const int mrow = w * 16 + l15;  // A-fragment row
    const int kb   = quad * 8;      // k offset within 32-chunk

    if (t < ET) s_rec[t] = adj_at(adj, is64, (long long)NEDGES + e0 + t);

    // ---- Stage state as bf16: 64 edges x 288 (72 float4 gathers each) ----
    for (int idx = t; idx < ET * 72; idx += 256) {
        int e = idx / 72, c = idx % 72;
        float4 v;
        if (c < 32) {
            int s = adj_at(adj, is64, e0 + e);
            v = ((const float4*)(x + (long long)s * HDIM))[c];
        } else if (c < 64) {
            int r = adj_at(adj, is64, (long long)NEDGES + e0 + e);
            v = ((const float4*)(x + (long long)r * HDIM))[c - 32];
        } else {
            v = ((const float4*)(inv + (long long)(e0 + e) * NINV))[c - 64];
        }
        ushort4 o;
        o.x = f2bf(v.x); o.y = f2bf(v.y); o.z = f2bf(v.z); o.w = f2bf(v.w);
        *(ushort4*)&s_state[e][c * 4] = o;
    }

    // ---- Stage first B tile (Wm1t k0=0): 128 rows x 64B, 2 x 16B per thread ----
    {
        float4 r0 = *(const float4*)(Wm1t + (t >> 2) * K1 + (t & 3) * 8);
        float4 r1 = *(const float4*)(Wm1t + ((t >> 2) + 64) * K1 + (t & 3) * 8);
        *(float4*)&s_b[(t >> 2)][(t & 3) * 8]      = r0;
        *(float4*)&s_b[(t >> 2) + 64][(t & 3) * 8] = r1;
    }
    __syncthreads();

    floatx4 acc[8];
    #pragma unroll
    for (int nt = 0; nt < 8; ++nt) {
        float bv = bm1[nt * 16 + l15];
        acc[nt] = (floatx4){bv, bv, bv, bv};
    }

    float4 p0, p1;

    // ---- Layer 1: state[64x288] @ Wm1[288x128], 9 K-steps ----
    #pragma unroll
    for (int s = 0; s < 9; ++s) {
        if (s < 8) {   // prefetch next Wm1t tile to regs
            int k0 = (s + 1) * 32;
            p0 = *(const float4*)(Wm1t + (t >> 2) * K1 + k0 + (t & 3) * 8);
            p1 = *(const float4*)(Wm1t + ((t >> 2) + 64) * K1 + k0 + (t & 3) * 8);
        } else {       // prefetch Wm2t tile 0
            p0 = *(const float4*)(Wm2t + (t >> 2) * HDIM + (t & 3) * 8);
            p1 = *(const float4*)(Wm2t + ((t >> 2) + 64) * HDIM + (t & 3) * 8);
        }
        short8 a = *(const short8*)&s_state[mrow][s * 32 + kb];
        #pragma unroll
        for (int nt = 0; nt < 8; ++nt) {
            short8 b = *(const short8*)&s_b[nt * 16 + l15][kb];
            acc[nt] = __builtin_amdgcn_mfma_f32_16x16x32_bf16(a, b, acc[nt], 0, 0, 0);
        }
        __syncthreads();
        *(float4*)&s_b[(t >> 2)][(t & 3) * 8]      = p0;
        *(float4*)&s_b[(t >> 2) + 64][(t & 3) * 8] = p1;
        __syncthreads();
    }

    // ---- L1 epilogue: SiLU -> h into s_state cols 0..127 (own rows only) ----
    #pragma unroll
    for (int nt = 0; nt < 8; ++nt) {
        int col = nt * 16 + l15;
        #pragma unroll
        for (int r = 0; r < 4; ++r)
            s_state[w * 16 + quad * 4 + r][col] = f2bf(silu_f(acc[nt][r]));
        float bv = bm2[col];
        acc[nt] = (floatx4){bv, bv, bv, bv};
    }

    // ---- Layer 2: h[64x128] @ Wm2[128x128], 4 K-steps ----
    #pragma unroll
    for (int s = 0; s < 4; ++s) {
        if (s < 3) {
            int k0 = (s + 1) * 32;
            p0 = *(const float4*)(Wm2t + (t >> 2) * HDIM + k0 + (t & 3) * 8);
            p1 = *(const float4*)(Wm2t + ((t >> 2) + 64) * HDIM + k0 + (t & 3) * 8);
        }
        short8 a = *(const short8*)&s_state[mrow][s * 32 + kb];
        #pragma unroll
        for (int nt = 0; nt < 8; ++nt) {
            short8 b = *(const short8*)&s_b[nt * 16 + l15][kb];
            acc[nt] = __builtin_amdgcn_mfma_f32_16x16x32_bf16(a, b, acc[nt], 0, 0, 0);
        }
        if (s < 3) {
            __syncthreads();
            *(float4*)&s_b[(t >> 2)][(t & 3) * 8]      = p0;
            *(float4*)&s_b[(t >> 2) + 64][(t & 3) * 8] = p1;
            __syncthreads();
        }
    }

    // ---- Epilogue: SiLU, gate (quad shuffle-reduce), atomic scatter ----
    float we[8];
    #pragma unroll
    for (int nt = 0; nt < 8; ++nt) we[nt] = We[nt * 16 + l15];
    float be0 = be[0];

    #pragma unroll
    for (int nt = 0; nt < 8; ++nt)
        #pragma unroll
        for (int r = 0; r < 4; ++r)
            acc[nt][r] = silu_f(acc[nt][r]);

    #pragma unroll
    for (int r = 0; r < 4; ++r) {
        float partial = 0.f;
        #pragma unroll
        for (int nt = 0; nt < 8; ++nt) partial += acc[nt][r] * we[nt];
        partial += __shfl_xor(partial, 1);
        partial += __shfl_xor(partial, 2);
        partial += __shfl_xor(partial, 4);
        partial += __shfl_xor(partial, 8);
        float g = 1.0f / (1.0f + __expf(-(partial + be0)));
        int e = w * 16 + quad * 4 + r;
        long long base = (long long)s_rec[e] * HDIM;
        #pragma unroll
        for (int nt = 0; nt < 8; ++nt)
            atomicAdd(aggr + base + nt * 16 + l15, acc[nt][r] * g);
    }
}

__global__ __launch_bounds__(256) void node_kernel(
    const float* __restrict__ x, const float* __restrict__ aggr,
    const float* __restrict__ Wu1, const float* __restrict__ bu1,
    const float* __restrict__ Wu2, const float* __restrict__ bu2,
    float* __restrict__ out)
{
    __shared__ float s_in[NT][USTRIDE];
    __shared__ float s_t[NT][HSTRIDE];

    const int t  = threadIdx.x;
    const int n0 = blockIdx.x * NT;

    for (int idx = t; idx < NT * 64; idx += 256) {
        int n = idx / 64, c = idx % 64;
        if (n0 + n < NNODES) {
            float4 v = (c < 32) ? ((const float4*)(x    + (long long)(n0 + n) * HDIM))[c]
                                : ((const float4*)(aggr + (long long)(n0 + n) * HDIM))[c - 32];
            *(float4*)&s_in[n][c * 4] = v;
        }
    }
    __syncthreads();

    const int jg = t & 31;
    const int ng = t >> 5;
    const int nb = ng * 4;

    float4 a0, a1, a2, a3;

    {
        float4 b = ((const float4*)bu1)[jg];
        a0 = b; a1 = b; a2 = b; a3 = b;
        const float4* W = (const float4*)Wu1;
        #pragma unroll 4
        for (int k = 0; k < 2 * HDIM; ++k) {
            float4 w = W[k * 32 + jg];
            float s0 = s_in[nb + 0][k];
            float s1 = s_in[nb + 1][k];
            float s2 = s_in[nb + 2][k];
            float s3 = s_in[nb + 3][k];
            FMA4(a0, s0, w); FMA4(a1, s1, w); FMA4(a2, s2, w); FMA4(a3, s3, w);
        }
        *(float4*)&s_t[nb + 0][jg * 4] = make_float4(silu_f(a0.x), silu_f(a0.y), silu_f(a0.z), silu_f(a0.w));
        *(float4*)&s_t[nb + 1][jg * 4] = make_float4(silu_f(a1.x), silu_f(a1.y), silu_f(a1.z), silu_f(a1.w));
        *(float4*)&s_t[nb + 2][jg * 4] = make_float4(silu_f(a2.x), silu_f(a2.y), silu_f(a2.z), silu_f(a2.w));
        *(float4*)&s_t[nb + 3][jg * 4] = make_float4(silu_f(a3.x), silu_f(a3.y), silu_f(a3.z), silu_f(a3.w));
    }
    __syncthreads();

    {
        float4 b = ((const float4*)bu2)[jg];
        a0 = b; a1 = b; a2 = b; a3 = b;
        const float4* W = (const float4*)Wu2;
        #pragma unroll 4
        for (int k = 0; k < HDIM; ++k) {
            float4 w = W[k * 32 + jg];
            float s0 = s_t[nb + 0][k];
            float s1 = s_t[nb + 1][k];
            float s2 = s_t[nb + 2][k];
            float s3 = s_t[nb + 3][k];
            FMA4(a0, s0, w); FMA4(a1, s1, w); FMA4(a2, s2, w); FMA4(a3, s3, w);
        }
        #pragma unroll
        for (int i = 0; i < 4; ++i) {
            int n = nb + i;
            if (n0 + n < NNODES) {
                float4 acc = (i == 0) ? a0 : (i == 1) ? a1 : (i == 2) ? a2 : a3;
                float4 xv = *(float4*)&s_in[n][jg * 4];
                float4 o = make_float4(xv.x + acc.x, xv.y + acc.y, xv.z + acc.z, xv.w + acc.w);
                ((float4*)(out + (long long)(n0 + n) * HDIM))[jg] = o;
            }
        }
    }
}

extern "C" void kernel_launch(void* const* d_in, const int* in_sizes, int n_in,
                              void* d_out, int out_size, void* d_ws, size_t ws_size,
                              hipStream_t stream)
{
    const float* x   = (const float*)d_in[0];
    const void*  adj = d_in[1];
    const float* inv = (const float*)d_in[2];
    const float* Wm1 = (const float*)d_in[3];
    const float* bm1 = (const float*)d_in[4];
    const float* Wm2 = (const float*)d_in[5];
    const float* bm2 = (const float*)d_in[6];
    const float* We  = (const float*)d_in[7];
    const float* be  = (const float*)d_in[8];
    const float* Wu1 = (const float*)d_in[9];
    const float* bu1 = (const float*)d_in[10];
    const float* Wu2 = (const float*)d_in[11];
    const float* bu2 = (const float*)d_in[12];
    float* out = (float*)d_out;

    char* ws = (char*)d_ws;
    float* aggr = (float*)ws;                                  // 25,600,000 B
    int* flag = (int*)(ws + (size_t)NNODES * HDIM * 4);
    unsigned short* Wm1t = (unsigned short*)(ws + (size_t)NNODES * HDIM * 4 + 16);
    unsigned short* Wm2t = Wm1t + 128 * K1;                    // +73,728 B

    hipMemsetAsync(aggr, 0, (size_t)NNODES * HDIM * sizeof(float), stream);
    detect_idx64<<<1, 256, 0, stream>>>((const int*)adj, flag);
    prep_weights<<<(128 * K1 + 128 * HDIM + 255) / 256, 256, 0, stream>>>(Wm1, Wm2, Wm1t, Wm2t);
    edge_kernel<<<NEDGES / ET, 256, 0, stream>>>(x, adj, flag, inv,
                                                 Wm1t, bm1, Wm2t, bm2, We, be, aggr);
    node_kernel<<<(NNODES + NT - 1) / NT, 256, 0, stream>>>(x, aggr,
                                                            Wu1, bu1, Wu2, bu2, out);
}

// Round 3
// 675.139 us; speedup vs baseline: 3.4668x; 1.4974x over previous
//
#include <hip/hip_runtime.h>
#include <math.h>

#define NNODES 50000
#define NEDGES 800000
#define HDIM 128
#define NINV 32
#define K1 288            // 2H + NINV
#define NTILES_E 25000    // NEDGES / 32
#define NTILES_N 1563     // ceil(NNODES / 32)

#define W1STRIDE 296      // ushorts per W1 LDS row (288+8): 148 dw == 20 mod 32 -> uniform banks, 16B aligned
#define U1STRIDE 264      // ushorts per Wu1 LDS row (256+8): 132 dw == 4 mod 32, 16B aligned
#define HSTRIDE 132       // h-buffer row stride in ushorts (128+4): 66 dw == 2 mod 32 -> u16 writes 2-way free

typedef float floatx4 __attribute__((ext_vector_type(4)));
typedef short short8  __attribute__((ext_vector_type(8)));

union V4S8 { uint4 u; short8 s; int2 d[2]; };

__device__ __forceinline__ float silu_f(float z) { return z / (1.0f + __expf(-z)); }

__device__ __forceinline__ unsigned short f2bf_rne(float f) {
    unsigned u = __float_as_uint(f);
    u += 0x7fffu + ((u >> 16) & 1u);
    return (unsigned short)(u >> 16);
}

// pack hi16(bf-truncate) of two floats into one dword: [lo | hi<<16]
__device__ __forceinline__ unsigned pk_bf(float hi, float lo) {
    return __builtin_amdgcn_perm(__float_as_uint(hi), __float_as_uint(lo), 0x07060302);
}

__device__ __forceinline__ short8 cvt8(float4 f0, float4 f1) {
    V4S8 v;
    v.u.x = pk_bf(f0.y, f0.x);
    v.u.y = pk_bf(f0.w, f0.z);
    v.u.z = pk_bf(f1.y, f1.x);
    v.u.w = pk_bf(f1.w, f1.z);
    return v.s;
}

__device__ __forceinline__ int adj_at(const void* adj, int is64, long long pos) {
    if (is64) return (int)((const long long*)adj)[pos];
    return ((const int*)adj)[pos];
}

__global__ __launch_bounds__(256) void detect_idx64(const int* __restrict__ adj32,
                                                    int* __restrict__ flag) {
    __shared__ int any_nz;
    if (threadIdx.x == 0) any_nz = 0;
    __syncthreads();
    int v = adj32[threadIdx.x * 2 + 1];
    if (v != 0) atomicOr(&any_nz, 1);
    __syncthreads();
    if (threadIdx.x == 0) *flag = (any_nz == 0) ? 1 : 0;
}

// Transpose + bf16(RNE) all four weight matrices: Wt[n][k] = bf16(W[k][n]).
__global__ __launch_bounds__(256) void prep_weights(
    const float* __restrict__ Wm1, const float* __restrict__ Wm2,
    const float* __restrict__ Wu1, const float* __restrict__ Wu2,
    unsigned short* __restrict__ Wm1t, unsigned short* __restrict__ Wm2t,
    unsigned short* __restrict__ Wu1t, unsigned short* __restrict__ Wu2t)
{
    int i = blockIdx.x * 256 + threadIdx.x;
    if (i < 128 * K1) {
        int n = i / K1, k = i % K1;
        Wm1t[i] = f2bf_rne(Wm1[k * HDIM + n]);
    } else if ((i -= 128 * K1) < 128 * HDIM) {
        int n = i / HDIM, k = i % HDIM;
        Wm2t[i] = f2bf_rne(Wm2[k * HDIM + n]);
    } else if ((i -= 128 * HDIM) < 128 * 256) {
        int n = i / 256, k = i % 256;
        Wu1t[i] = f2bf_rne(Wu1[k * HDIM + n]);
    } else if ((i -= 128 * 256) < 128 * HDIM) {
        int n = i / HDIM, k = i % HDIM;
        Wu2t[i] = f2bf_rne(Wu2[k * HDIM + n]);
    }
}

// ---------------- Edge kernel: persistent, barrier-free K-loop ----------------
__global__ __launch_bounds__(512, 2) void edge_kernel(
    const float* __restrict__ x, const void* __restrict__ adj,
    const int* __restrict__ flagp, const float* __restrict__ inv,
    const unsigned short* __restrict__ Wm1t, const float* __restrict__ bm1,
    const unsigned short* __restrict__ Wm2t, const float* __restrict__ bm2,
    const float* __restrict__ We, const float* __restrict__ be,
    float* __restrict__ aggr)
{
    __shared__ unsigned short s_w1[128 * W1STRIDE];      // 75,776 B
    __shared__ unsigned short s_h[8 * 32 * HSTRIDE];     // 67,584 B (wave-private slices)

    const int t    = threadIdx.x;
    const int is64 = *flagp;
    const int l    = t & 63;
    const int wid  = t >> 6;
    const int l15  = l & 15;
    const int quad = l >> 4;

    // Fill W1 LDS (once)
    for (int idx = t; idx < 128 * 36; idx += 512) {
        int n = idx / 36, c = idx % 36;
        *(uint4*)&s_w1[n * W1STRIDE + c * 8] = *(const uint4*)(Wm1t + n * K1 + c * 8);
    }

    // W2 B-fragments resident in 128 VGPRs
    short8 w2f[4][8];
    #pragma unroll
    for (int ks = 0; ks < 4; ++ks)
        #pragma unroll
        for (int nt = 0; nt < 8; ++nt)
            w2f[ks][nt] = *(const short8*)(Wm2t + (nt * 16 + l15) * HDIM + ks * 32 + quad * 8);

    __syncthreads();   // the only barrier

    unsigned short* hbuf = s_h + wid * (32 * HSTRIDE);
    const int gwave  = blockIdx.x * 8 + wid;
    const int nwaves = gridDim.x * 8;

    for (int tile = gwave; tile < NTILES_E; tile += nwaves) {
        const int e0 = tile * 32;
        int se[2], re[2];
        unsigned offS[2], offR[2], offI[2];
        #pragma unroll
        for (int m = 0; m < 2; ++m) {
            se[m] = adj_at(adj, is64, e0 + m * 16 + l15);
            re[m] = adj_at(adj, is64, (long long)NEDGES + e0 + m * 16 + l15);
            offS[m] = (unsigned)se[m] * HDIM;
            offR[m] = (unsigned)re[m] * HDIM;
            offI[m] = (unsigned)(e0 + m * 16 + l15) * NINV;
        }

        auto aptr = [&](int s, int m) -> const float* {
            if (s < 4)  return x   + offS[m] + s * 32 + quad * 8;
            if (s < 8)  return x   + offR[m] + (s - 4) * 32 + quad * 8;
            return             inv + offI[m] + quad * 8;
        };

        // 2-deep prefetch pipeline for A fragments
        float4 F0[2][2], F1[2][2];
        #pragma unroll
        for (int m = 0; m < 2; ++m) {
            const float* p = aptr(0, m); F0[m][0] = ((const float4*)p)[0]; F0[m][1] = ((const float4*)p)[1];
            const float* q = aptr(1, m); F1[m][0] = ((const float4*)q)[0]; F1[m][1] = ((const float4*)q)[1];
        }

        floatx4 acc[2][8];
        #pragma unroll
        for (int nt = 0; nt < 8; ++nt) {
            float bv = bm1[nt * 16 + l15];
            acc[0][nt] = (floatx4){bv, bv, bv, bv};
            acc[1][nt] = acc[0][nt];
        }

        // ---- Layer 1: 9 K-steps, B from resident LDS, A from global via regs ----
        #pragma unroll
        for (int s = 0; s < 9; ++s) {
            short8 a[2];
            #pragma unroll
            for (int m = 0; m < 2; ++m) {
                float4 f0 = (s & 1) ? F1[m][0] : F0[m][0];
                float4 f1 = (s & 1) ? F1[m][1] : F0[m][1];
                a[m] = cvt8(f0, f1);
                if (s + 2 <= 8) {
                    const float* p = aptr(s + 2, m);
                    if (s & 1) { F1[m][0] = ((const float4*)p)[0]; F1[m][1] = ((const float4*)p)[1]; }
                    else       { F0[m][0] = ((const float4*)p)[0]; F0[m][1] = ((const float4*)p)[1]; }
                }
            }
            const unsigned short* wbase = s_w1 + l15 * W1STRIDE + s * 32 + quad * 8;
            #pragma unroll
            for (int nt = 0; nt < 8; ++nt) {
                short8 b = *(const short8*)(wbase + nt * 16 * W1STRIDE);
                acc[0][nt] = __builtin_amdgcn_mfma_f32_16x16x32_bf16(a[0], b, acc[0][nt], 0, 0, 0);
                acc[1][nt] = __builtin_amdgcn_mfma_f32_16x16x32_bf16(a[1], b, acc[1][nt], 0, 0, 0);
            }
        }

        // ---- L1 epilogue: SiLU -> bf16 h into wave-private LDS (no barrier) ----
        #pragma unroll
        for (int m = 0; m < 2; ++m)
            #pragma unroll
            for (int nt = 0; nt < 8; ++nt)
                #pragma unroll
                for (int r = 0; r < 4; ++r) {
                    float hv = silu_f(acc[m][nt][r]);
                    hbuf[(m * 16 + quad * 4 + r) * HSTRIDE + nt * 16 + l15] =
                        (unsigned short)(__float_as_uint(hv) >> 16);
                }

        #pragma unroll
        for (int nt = 0; nt < 8; ++nt) {
            float bv = bm2[nt * 16 + l15];
            acc[0][nt] = (floatx4){bv, bv, bv, bv};
            acc[1][nt] = acc[0][nt];
        }

        // ---- Layer 2: 4 K-steps, B from registers, A from wave-private LDS ----
        #pragma unroll
        for (int ks = 0; ks < 4; ++ks) {
            short8 a2[2];
            #pragma unroll
            for (int m = 0; m < 2; ++m) {
                int base = (m * 16 + l15) * HSTRIDE + ks * 32 + quad * 8;
                V4S8 v;
                v.d[0] = *(const int2*)(hbuf + base);
                v.d[1] = *(const int2*)(hbuf + base + 4);
                a2[m] = v.s;
            }
            #pragma unroll
            for (int nt = 0; nt < 8; ++nt) {
                acc[0][nt] = __builtin_amdgcn_mfma_f32_16x16x32_bf16(a2[0], w2f[ks][nt], acc[0][nt], 0, 0, 0);
                acc[1][nt] = __builtin_amdgcn_mfma_f32_16x16x32_bf16(a2[1], w2f[ks][nt], acc[1][nt], 0, 0, 0);
            }
        }

        // ---- Epilogue: SiLU, gate, atomic scatter ----
        float be0 = be[0];
        #pragma unroll
        for (int m = 0; m < 2; ++m) {
            #pragma unroll
            for (int nt = 0; nt < 8; ++nt)
                #pragma unroll
                for (int r = 0; r < 4; ++r)
                    acc[m][nt][r] = silu_f(acc[m][nt][r]);

            #pragma unroll
            for (int r = 0; r < 4; ++r) {
                float part = 0.f;
                #pragma unroll
                for (int nt = 0; nt < 8; ++nt)
                    part = fmaf(acc[m][nt][r], We[nt * 16 + l15], part);
                part += __shfl_xor(part, 1);
                part += __shfl_xor(part, 2);
                part += __shfl_xor(part, 4);
                part += __shfl_xor(part, 8);
                float g = 1.0f / (1.0f + __expf(-(part + be0)));
                int rr = __shfl(re[m], quad * 4 + r, 16);
                float* dst = aggr + (long long)rr * HDIM + l15;
                #pragma unroll
                for (int nt = 0; nt < 8; ++nt)
                    atomicAdd(dst + nt * 16, acc[m][nt][r] * g);
            }
        }
    }
}

// ---------------- Node kernel: same structure, no gather/gate/atomics ----------------
__global__ __launch_bounds__(256) void node_kernel(
    const float* __restrict__ x, const float* __restrict__ aggr,
    const unsigned short* __restrict__ Wu1t, const float* __restrict__ bu1,
    const unsigned short* __restrict__ Wu2t, const float* __restrict__ bu2,
    float* __restrict__ out)
{
    __shared__ unsigned short s_u1[128 * U1STRIDE];      // 67,584 B
    __shared__ unsigned short s_h[4 * 32 * HSTRIDE];     // 33,792 B

    const int t    = threadIdx.x;
    const int l    = t & 63;
    const int wid  = t >> 6;
    const int l15  = l & 15;
    const int quad = l >> 4;

    for (int idx = t; idx < 128 * 32; idx += 256) {
        int n = idx / 32, c = idx % 32;
        *(uint4*)&s_u1[n * U1STRIDE + c * 8] = *(const uint4*)(Wu1t + n * 256 + c * 8);
    }

    short8 w2f[4][8];
    #pragma unroll
    for (int ks = 0; ks < 4; ++ks)
        #pragma unroll
        for (int nt = 0; nt < 8; ++nt)
            w2f[ks][nt] = *(const short8*)(Wu2t + (nt * 16 + l15) * HDIM + ks * 32 + quad * 8);

    __syncthreads();

    unsigned short* hbuf = s_h + wid * (32 * HSTRIDE);
    const int tile = blockIdx.x * 4 + wid;
    if (tile >= NTILES_N) return;
    const int n0 = tile * 32;

    unsigned offX[2];
    #pragma unroll
    for (int m = 0; m < 2; ++m) {
        int row = n0 + m * 16 + l15;
        if (row >= NNODES) row = NNODES - 1;
        offX[m] = (unsigned)row * HDIM;
    }

    floatx4 acc[2][8];
    #pragma unroll
    for (int nt = 0; nt < 8; ++nt) {
        float bv = bu1[nt * 16 + l15];
        acc[0][nt] = (floatx4){bv, bv, bv, bv};
        acc[1][nt] = acc[0][nt];
    }

    // Layer 1: K=256 ([x | aggr]), 8 K-steps
    #pragma unroll
    for (int s = 0; s < 8; ++s) {
        short8 a[2];
        #pragma unroll
        for (int m = 0; m < 2; ++m) {
            const float* p = (s < 4) ? (x + offX[m] + s * 32 + quad * 8)
                                     : (aggr + offX[m] + (s - 4) * 32 + quad * 8);
            float4 f0 = ((const float4*)p)[0];
            float4 f1 = ((const float4*)p)[1];
            a[m] = cvt8(f0, f1);
        }
        const unsigned short* wbase = s_u1 + l15 * U1STRIDE + s * 32 + quad * 8;
        #pragma unroll
        for (int nt = 0; nt < 8; ++nt) {
            short8 b = *(const short8*)(wbase + nt * 16 * U1STRIDE);
            acc[0][nt] = __builtin_amdgcn_mfma_f32_16x16x32_bf16(a[0], b, acc[0][nt], 0, 0, 0);
            acc[1][nt] = __builtin_amdgcn_mfma_f32_16x16x32_bf16(a[1], b, acc[1][nt], 0, 0, 0);
        }
    }

    #pragma unroll
    for (int m = 0; m < 2; ++m)
        #pragma unroll
        for (int nt = 0; nt < 8; ++nt)
            #pragma unroll
            for (int r = 0; r < 4; ++r) {
                float hv = silu_f(acc[m][nt][r]);
                hbuf[(m * 16 + quad * 4 + r) * HSTRIDE + nt * 16 + l15] =
                    (unsigned short)(__float_as_uint(hv) >> 16);
            }

    #pragma unroll
    for (int nt = 0; nt < 8; ++nt) {
        float bv = bu2[nt * 16 + l15];
        acc[0][nt] = (floatx4){bv, bv, bv, bv};
        acc[1][nt] = acc[0][nt];
    }

    #pragma unroll
    for (int ks = 0; ks < 4; ++ks) {
        short8 a2[2];
        #pragma unroll
        for (int m = 0; m < 2; ++m) {
            int base = (m * 16 + l15) * HSTRIDE + ks * 32 + quad * 8;
            V4S8 v;
            v.d[0] = *(const int2*)(hbuf + base);
            v.d[1] = *(const int2*)(hbuf + base + 4);
            a2[m] = v.s;
        }
        #pragma unroll
        for (int nt = 0; nt < 8; ++nt) {
            acc[0][nt] = __builtin_amdgcn_mfma_f32_16x16x32_bf16(a2[0], w2f[ks][nt], acc[0][nt], 0, 0, 0);
            acc[1][nt] = __builtin_amdgcn_mfma_f32_16x16x32_bf16(a2[1], w2f[ks][nt], acc[1][nt], 0, 0, 0);
        }
    }

    // Residual + store (no activation after layer 2)
    #pragma unroll
    for (int m = 0; m < 2; ++m)
        #pragma unroll
        for (int r = 0; r < 4; ++r) {
            int row = n0 + m * 16 + quad * 4 + r;
            if (row < NNODES) {
                #pragma unroll
                for (int nt = 0; nt < 8; ++nt) {
                    int col = nt * 16 + l15;
                    out[(long long)row * HDIM + col] = x[(long long)row * HDIM + col] + acc[m][nt][r];
                }
            }
        }
}

extern "C" void kernel_launch(void* const* d_in, const int* in_sizes, int n_in,
                              void* d_out, int out_size, void* d_ws, size_t ws_size,
                              hipStream_t stream)
{
    const float* x   = (const float*)d_in[0];
    const void*  adj = d_in[1];
    const float* inv = (const float*)d_in[2];
    const float* Wm1 = (const float*)d_in[3];
    const float* bm1 = (const float*)d_in[4];
    const float* Wm2 = (const float*)d_in[5];
    const float* bm2 = (const float*)d_in[6];
    const float* We  = (const float*)d_in[7];
    const float* be  = (const float*)d_in[8];
    const float* Wu1 = (const float*)d_in[9];
    const float* bu1 = (const float*)d_in[10];
    const float* Wu2 = (const float*)d_in[11];
    const float* bu2 = (const float*)d_in[12];
    float* out = (float*)d_out;

    char* ws = (char*)d_ws;
    float* aggr = (float*)ws;
    size_t off = (size_t)NNODES * HDIM * 4;
    int* flag = (int*)(ws + off);            off += 16;
    unsigned short* Wm1t = (unsigned short*)(ws + off);  off += 128 * K1 * 2;
    unsigned short* Wm2t = (unsigned short*)(ws + off);  off += 128 * HDIM * 2;
    unsigned short* Wu1t = (unsigned short*)(ws + off);  off += 128 * 256 * 2;
    unsigned short* Wu2t = (unsigned short*)(ws + off);

    hipMemsetAsync(aggr, 0, (size_t)NNODES * HDIM * sizeof(float), stream);
    detect_idx64<<<1, 256, 0, stream>>>((const int*)adj, flag);
    prep_weights<<<400, 256, 0, stream>>>(Wm1, Wm2, Wu1, Wu2, Wm1t, Wm2t, Wu1t, Wu2t);
    edge_kernel<<<256, 512, 0, stream>>>(x, adj, flag, inv,
                                         Wm1t, bm1, Wm2t, bm2, We, be, aggr);
    node_kernel<<<(NTILES_N + 3) / 4, 256, 0, stream>>>(x, aggr,
                                                        Wu1t, bu1, Wu2t, bu2, out);
}